// Round 12
// baseline (105.309 us; speedup 1.0000x reference)
//
#include <hip/hip_runtime.h>

#define N_ROWS 8192
#define DIM 128
#define NCLS 43
#define TILE 128
#define TILES 64            // N_ROWS / 128
#define NPAIRS 2080         // TILES*(TILES+1)/2

typedef __attribute__((ext_vector_type(4))) float float4v;
typedef __attribute__((ext_vector_type(4))) int   int4v;
typedef __attribute__((ext_vector_type(8))) int   int8v;
typedef __attribute__((address_space(1))) const void global_cvoid;
typedef __attribute__((address_space(3))) void lds_void;

#define SM_B    16384       // LDS: A 16KB | B 16KB | red 128B | flag
#define SM_RED  32768
#define SM_FLAG 32896
#define SM_SIZE 33024       // < 40 KB -> 4 blocks/CU

// ---- kernel A: x->fp8(e4m3 RNE), fp32 row sq-norms, zero done-counter ----
__global__ void __launch_bounds__(256) prep_kernel(
        const float* __restrict__ x,
        float* __restrict__ sq,
        unsigned char* __restrict__ xq,
        int* __restrict__ counter) {
    if (blockIdx.x == 0 && threadIdx.x == 0) *counter = 0;
    int wave = threadIdx.x >> 6;
    int lane = threadIdx.x & 63;
    int half = lane >> 5, l32 = lane & 31;
    int row  = blockIdx.x * 8 + wave * 2 + half;
    const float4 v = *(const float4*)(x + (size_t)row * DIM + l32 * 4);
    int pk = __builtin_amdgcn_cvt_pk_fp8_f32(v.x, v.y, 0, 0);
    pk     = __builtin_amdgcn_cvt_pk_fp8_f32(v.z, v.w, pk, 1);
    *(int*)(xq + (size_t)row * DIM + l32 * 4) = pk;
    float s = v.x * v.x + v.y * v.y + v.z * v.z + v.w * v.w;
    #pragma unroll
    for (int off = 16; off > 0; off >>= 1) s += __shfl_down(s, off);
    if (l32 == 0) sq[row] = s;
}

// ---- kernel B: 128x128 MX-fp8 K=128 MFMA tiles + last-block fused finish ----
__global__ void __launch_bounds__(256, 4) tile_kernel(
        const unsigned char* __restrict__ xq,
        const float* __restrict__ sq,
        const int* __restrict__ y,
        float2* __restrict__ partials,
        int* __restrict__ counter,
        float* __restrict__ out) {
    __shared__ __align__(16) char smem[SM_SIZE];

    // decode linear block id -> (bi, bj) with bi <= bj
    int t = blockIdx.x;
    int bi = (int)((129.0f - sqrtf((float)(129 * 129 - 8 * t))) * 0.5f);
    if (bi < 0) bi = 0;
    if (bi > TILES - 1) bi = TILES - 1;
    while (bi * TILES - (bi * (bi - 1)) / 2 > t) --bi;
    while ((bi + 1) * TILES - ((bi + 1) * bi) / 2 <= t) ++bi;
    int bj = bi + (t - (bi * TILES - (bi * (bi - 1)) / 2));

    int wv   = threadIdx.x >> 6;
    int lane = threadIdx.x & 63;

    // async stage A+B (16 KB each) via global_load_lds, swizzle on SOURCE addr:
    // LDS slot p holds global chunk (r = p>>7, c = ((p>>4)&7) ^ (r&7))
    const char* srcA = (const char*)(xq + (size_t)bi * TILE * DIM);
    const char* srcB = (const char*)(xq + (size_t)bj * TILE * DIM);
    #pragma unroll
    for (int it = 0; it < 4; ++it) {
        int pbase = (it * 4 + wv) * 1024;
        int p = pbase + lane * 16;
        int r = p >> 7;
        int c = ((p >> 4) & 7) ^ (r & 7);
        int goff = (r << 7) + (c << 4);
        __builtin_amdgcn_global_load_lds(
            (global_cvoid*)(srcA + goff), (lds_void*)(smem + pbase), 16, 0, 0);
        __builtin_amdgcn_global_load_lds(
            (global_cvoid*)(srcB + goff), (lds_void*)(smem + SM_B + pbase), 16, 0, 0);
    }
    __syncthreads();   // drains DMA

    int m    = lane & 15;
    int quad = lane >> 4;
    int wr   = (wv >> 1) * 64;
    int wc   = (wv & 1) * 64;

    // prefetch epilogue j-values NOW so latency hides under ds_read/MFMA
    int giB = bi * TILE + wr + quad * 4;    // global row base (+ ti*16 + r)
    int gjB = bj * TILE + wc + m;           // global col base (+ tj*16)
    float sqj[4]; int yj[4];
    #pragma unroll
    for (int tj = 0; tj < 4; ++tj) {
        sqj[tj] = sq[gjB + tj * 16];
        yj[tj]  = y [gjB + tj * 16];
    }

    float4v acc[4][4];
    #pragma unroll
    for (int a = 0; a < 4; ++a)
        #pragma unroll
        for (int c = 0; c < 4; ++c) {
            float4v z = {0.f, 0.f, 0.f, 0.f};
            acc[a][c] = z;
        }

    // MX fp8 16x16x128: lane (m,quad) holds A[m][k], k = quad*32 + [0..31]
    int8v af[4];
    #pragma unroll
    for (int ti = 0; ti < 4; ++ti) {
        int R = wr + ti * 16 + m;
        const char* base = smem + R * 128;
        int4v lo = *(const int4v*)(base + ((( 2 * quad    ) ^ (R & 7)) << 4));
        int4v hi = *(const int4v*)(base + (((2 * quad + 1) ^ (R & 7)) << 4));
        int8v v; v[0]=lo[0]; v[1]=lo[1]; v[2]=lo[2]; v[3]=lo[3];
                 v[4]=hi[0]; v[5]=hi[1]; v[6]=hi[2]; v[7]=hi[3];
        af[ti] = v;
    }
    #pragma unroll
    for (int tj = 0; tj < 4; ++tj) {
        int R = wc + tj * 16 + m;
        const char* base = smem + SM_B + R * 128;
        int4v lo = *(const int4v*)(base + ((( 2 * quad    ) ^ (R & 7)) << 4));
        int4v hi = *(const int4v*)(base + (((2 * quad + 1) ^ (R & 7)) << 4));
        int8v bv; bv[0]=lo[0]; bv[1]=lo[1]; bv[2]=lo[2]; bv[3]=lo[3];
                  bv[4]=hi[0]; bv[5]=hi[1]; bv[6]=hi[2]; bv[7]=hi[3];
        #pragma unroll
        for (int ti = 0; ti < 4; ++ti)
            acc[ti][tj] = __builtin_amdgcn_mfma_scale_f32_16x16x128_f8f6f4(
                af[ti], bv, acc[ti][tj],
                0, 0,                       // fmtA = fmtB = fp8 e4m3
                0, 0x7F7F7F7F,              // scale_a = 1.0
                0, 0x7F7F7F7F);             // scale_b = 1.0
    }

    // ---- lean epilogue: pos needs only dot; neg via conservative guard ----
    float sqjmin = fminf(fminf(sqj[0], sqj[1]), fminf(sqj[2], sqj[3]));
    float posD = 0.f, dotmax = -3e38f, sqimin = 3e38f;

    if (bi != bj) {
        #pragma unroll
        for (int ti = 0; ti < 4; ++ti) {
            #pragma unroll
            for (int r = 0; r < 4; ++r) {
                int gi = giB + ti * 16 + r;
                float sqi = sq[gi]; int yi = y[gi];
                sqimin = fminf(sqimin, sqi);
                #pragma unroll
                for (int tj = 0; tj < 4; ++tj) {
                    float d = acc[ti][tj][r];
                    posD += (yi == yj[tj]) ? d : 0.f;
                    dotmax = fmaxf(dotmax, d);
                }
            }
        }
    } else {
        #pragma unroll
        for (int ti = 0; ti < 4; ++ti) {
            #pragma unroll
            for (int r = 0; r < 4; ++r) {
                int gi = giB + ti * 16 + r;
                float sqi = sq[gi]; int yi = y[gi];
                sqimin = fminf(sqimin, sqi);
                #pragma unroll
                for (int tj = 0; tj < 4; ++tj) {
                    bool self = (gi == gjB + tj * 16);
                    float d = acc[ti][tj][r];
                    posD += (yi == yj[tj] && !self) ? d : 0.f;
                    dotmax = fmaxf(dotmax, self ? -3e38f : d);
                }
            }
        }
    }

    // cold exact-neg fallback (never hot for this data: min nrm ~80 >> 1)
    float negS = 0.f;
    if (2.f * dotmax - sqimin - sqjmin >= -1.f) {
        #pragma unroll
        for (int ti = 0; ti < 4; ++ti)
            #pragma unroll
            for (int r = 0; r < 4; ++r) {
                int gi = giB + ti * 16 + r;
                float sqi = sq[gi]; int yi = y[gi];
                #pragma unroll
                for (int tj = 0; tj < 4; ++tj) {
                    int gj = gjB + tj * 16;
                    if (gi != gj && yi != yj[tj]) {
                        float nrm = fmaf(-2.f, acc[ti][tj][r], sqi + sqj[tj]);
                        negS += fmaxf(1.f - nrm, 0.f);
                    }
                }
            }
    }
    float wgt = (bi == bj) ? 1.f : 2.f;
    float posP = wgt * posD;    // sum of DOTS only (norm part added in finish)
    float negP = wgt * negS;

    #pragma unroll
    for (int off = 32; off > 0; off >>= 1) {
        posP += __shfl_down(posP, off);
        negP += __shfl_down(negP, off);
    }
    float2* wred = (float2*)(smem + SM_RED);
    int*    flag = (int*)(smem + SM_FLAG);
    if (lane == 0) wred[wv] = make_float2(posP, negP);
    __syncthreads();
    if (threadIdx.x == 0) {
        float2 a0 = wred[0], a1 = wred[1], a2 = wred[2], a3 = wred[3];
        partials[t] = make_float2(a0.x + a1.x + a2.x + a3.x,
                                  a0.y + a1.y + a2.y + a3.y);
        __threadfence();                      // release partials
        int old = atomicAdd(counter, 1);
        *flag = (old == NPAIRS - 1) ? 1 : 0;
    }
    __syncthreads();
    if (*flag == 0) return;

    // ===== fused finish (one 256-thread block, runs once) =====
    __threadfence();                          // acquire partials
    int tid = threadIdx.x;
    int* hists = (int*)smem;                  // 4 x 48 ints
    int* htot  = (int*)smem + 192;            // 48 ints
    float* fred = (float*)((int*)smem + 240); // 12 floats: sw[4], p[4], n[4]
    for (int i = tid; i < 240; i += 256) ((int*)smem)[i] = 0;
    __syncthreads();

    const int4*   y4  = (const int4*)y;       // 2048 int4
    const float4* sq4 = (const float4*)sq;    // 2048 float4
    #pragma unroll
    for (int k = 0; k < 8; ++k) {
        int4 v = y4[tid + k * 256];
        atomicAdd(&hists[wv * 48 + v.x], 1); atomicAdd(&hists[wv * 48 + v.y], 1);
        atomicAdd(&hists[wv * 48 + v.z], 1); atomicAdd(&hists[wv * 48 + v.w], 1);
    }
    __syncthreads();
    if (tid < 48) {
        int nc = hists[tid] + hists[48 + tid] + hists[96 + tid] + hists[144 + tid];
        htot[tid] = nc;
    }
    __syncthreads();

    // S_w = sum_i sq[i]*(n_{y_i}-1);  pos_norm_sum = 2*S_w - 2*pos_dot_sum
    float sw = 0.f;
    #pragma unroll
    for (int k = 0; k < 8; ++k) {
        int4   v = y4 [tid + k * 256];
        float4 s = sq4[tid + k * 256];
        sw += s.x * (float)(htot[v.x] - 1) + s.y * (float)(htot[v.y] - 1)
            + s.z * (float)(htot[v.z] - 1) + s.w * (float)(htot[v.w] - 1);
    }
    float p = 0.f, n = 0.f;
    for (int i = tid; i < NPAIRS; i += 256) {
        float2 v = partials[i];
        p += v.x; n += v.y;
    }
    #pragma unroll
    for (int off = 32; off > 0; off >>= 1) {
        sw += __shfl_down(sw, off);
        p  += __shfl_down(p, off);
        n  += __shfl_down(n, off);
    }
    if (lane == 0) { fred[wv] = sw; fred[4 + wv] = p; fred[8 + wv] = n; }
    __syncthreads();
    if (tid == 0) {
        float SW = fred[0] + fred[1] + fred[2] + fred[3];
        float PS = fred[4] + fred[5] + fred[6] + fred[7];
        float NS = fred[8] + fred[9] + fred[10] + fred[11];
        long long s2 = 0;
        for (int c = 0; c < NCLS; ++c) { long long h = htot[c]; s2 += h * h; }
        float posc = (float)(s2 - (long long)N_ROWS);
        float negc = (float)((long long)N_ROWS * N_ROWS - s2);
        out[0] = 0.5f * ((2.f * SW - 2.f * PS) / posc + NS / negc);
    }
}

extern "C" void kernel_launch(void* const* d_in, const int* in_sizes, int n_in,
                              void* d_out, int out_size, void* d_ws, size_t ws_size,
                              hipStream_t stream) {
    const float* x = (const float*)d_in[0];
    const int*   y = (const int*)d_in[1];
    float* out = (float*)d_out;

    char* ws = (char*)d_ws;
    int*            counter  = (int*)ws;                       // [0,4)
    float2*         partials = (float2*)(ws + 256);            // 2080 float2
    float*          sq       = (float*)(ws + 17152);           // 8192 floats
    unsigned char*  xq       = (unsigned char*)(ws + 50176);   // 8192*128 fp8 (1 MB)

    prep_kernel<<<N_ROWS / 8, 256, 0, stream>>>(x, sq, xq, counter);
    tile_kernel<<<NPAIRS, 256, 0, stream>>>(xq, sq, y, partials, counter, out);
}

// Round 13
// 71.728 us; speedup vs baseline: 1.4682x; 1.4682x over previous
//
#include <hip/hip_runtime.h>

#define N_ROWS 8192
#define DIM 128
#define NCLS 43
#define TILE 128
#define TILES 64            // N_ROWS / 128
#define NPAIRS 2080         // TILES*(TILES+1)/2

typedef __attribute__((ext_vector_type(4))) float float4v;
typedef __attribute__((ext_vector_type(4))) int   int4v;
typedef __attribute__((ext_vector_type(8))) int   int8v;
typedef __attribute__((address_space(1))) const void global_cvoid;
typedef __attribute__((address_space(3))) void lds_void;

#define SM_B    16384       // LDS: A 16KB | B 16KB | red 128B
#define SM_RED  32768
#define SM_SIZE 32896       // < 40 KB -> 4 blocks/CU

// ---- kernel A: x->fp8(e4m3 RNE), fp32 row sq-norms ----
__global__ void __launch_bounds__(256) prep_kernel(
        const float* __restrict__ x,
        float* __restrict__ sq,
        unsigned char* __restrict__ xq) {
    int wave = threadIdx.x >> 6;
    int lane = threadIdx.x & 63;
    int half = lane >> 5, l32 = lane & 31;
    int row  = blockIdx.x * 8 + wave * 2 + half;
    const float4 v = *(const float4*)(x + (size_t)row * DIM + l32 * 4);
    int pk = __builtin_amdgcn_cvt_pk_fp8_f32(v.x, v.y, 0, 0);
    pk     = __builtin_amdgcn_cvt_pk_fp8_f32(v.z, v.w, pk, 1);
    *(int*)(xq + (size_t)row * DIM + l32 * 4) = pk;
    float s = v.x * v.x + v.y * v.y + v.z * v.z + v.w * v.w;
    #pragma unroll
    for (int off = 16; off > 0; off >>= 1) s += __shfl_down(s, off);
    if (l32 == 0) sq[row] = s;
}

// ---- kernel B: 128x128 tile of S = X X^T via MX-fp8 K=128 MFMA ----
// 256 threads = 4 waves in 2x2 grid, each wave 64x64 outputs.
__global__ void __launch_bounds__(256, 4) tile_kernel(
        const unsigned char* __restrict__ xq,
        const float* __restrict__ sq,
        const int* __restrict__ y,
        float2* __restrict__ partials) {
    __shared__ __align__(16) char smem[SM_SIZE];

    // decode linear block id -> (bi, bj) with bi <= bj
    int t = blockIdx.x;
    int bi = (int)((129.0f - sqrtf((float)(129 * 129 - 8 * t))) * 0.5f);
    if (bi < 0) bi = 0;
    if (bi > TILES - 1) bi = TILES - 1;
    while (bi * TILES - (bi * (bi - 1)) / 2 > t) --bi;
    while ((bi + 1) * TILES - ((bi + 1) * bi) / 2 <= t) ++bi;
    int bj = bi + (t - (bi * TILES - (bi * (bi - 1)) / 2));

    int wv   = threadIdx.x >> 6;
    int lane = threadIdx.x & 63;

    // async stage A+B (16 KB each) via global_load_lds, swizzle on SOURCE addr:
    // LDS slot p holds global chunk (r = p>>7, c = ((p>>4)&7) ^ (r&7))
    const char* srcA = (const char*)(xq + (size_t)bi * TILE * DIM);
    const char* srcB = (const char*)(xq + (size_t)bj * TILE * DIM);
    #pragma unroll
    for (int it = 0; it < 4; ++it) {
        int pbase = (it * 4 + wv) * 1024;
        int p = pbase + lane * 16;
        int r = p >> 7;
        int c = ((p >> 4) & 7) ^ (r & 7);
        int goff = (r << 7) + (c << 4);
        __builtin_amdgcn_global_load_lds(
            (global_cvoid*)(srcA + goff), (lds_void*)(smem + pbase), 16, 0, 0);
        __builtin_amdgcn_global_load_lds(
            (global_cvoid*)(srcB + goff), (lds_void*)(smem + SM_B + pbase), 16, 0, 0);
    }
    __syncthreads();   // drains DMA

    int m    = lane & 15;
    int quad = lane >> 4;
    int wr   = (wv >> 1) * 64;
    int wc   = (wv & 1) * 64;

    // prefetch epilogue j-values NOW so latency hides under ds_read/MFMA
    int giB = bi * TILE + wr + quad * 4;    // global row base (+ ti*16 + r)
    int gjB = bj * TILE + wc + m;           // global col base (+ tj*16)
    float sqj[4]; int yj[4];
    #pragma unroll
    for (int tj = 0; tj < 4; ++tj) {
        sqj[tj] = sq[gjB + tj * 16];
        yj[tj]  = y [gjB + tj * 16];
    }

    float4v acc[4][4];
    #pragma unroll
    for (int a = 0; a < 4; ++a)
        #pragma unroll
        for (int c = 0; c < 4; ++c) {
            float4v z = {0.f, 0.f, 0.f, 0.f};
            acc[a][c] = z;
        }

    // MX fp8 16x16x128: lane (m,quad) holds A[m][k], k = quad*32 + [0..31]
    // = logical chunks 2q, 2q+1 of the 128 B row; stored chunk = c ^ (R&7).
    int8v af[4];
    #pragma unroll
    for (int ti = 0; ti < 4; ++ti) {
        int R = wr + ti * 16 + m;
        const char* base = smem + R * 128;
        int4v lo = *(const int4v*)(base + ((( 2 * quad    ) ^ (R & 7)) << 4));
        int4v hi = *(const int4v*)(base + (((2 * quad + 1) ^ (R & 7)) << 4));
        int8v v; v[0]=lo[0]; v[1]=lo[1]; v[2]=lo[2]; v[3]=lo[3];
                 v[4]=hi[0]; v[5]=hi[1]; v[6]=hi[2]; v[7]=hi[3];
        af[ti] = v;
    }
    #pragma unroll
    for (int tj = 0; tj < 4; ++tj) {
        int R = wc + tj * 16 + m;
        const char* base = smem + SM_B + R * 128;
        int4v lo = *(const int4v*)(base + ((( 2 * quad    ) ^ (R & 7)) << 4));
        int4v hi = *(const int4v*)(base + (((2 * quad + 1) ^ (R & 7)) << 4));
        int8v bv; bv[0]=lo[0]; bv[1]=lo[1]; bv[2]=lo[2]; bv[3]=lo[3];
                  bv[4]=hi[0]; bv[5]=hi[1]; bv[6]=hi[2]; bv[7]=hi[3];
        #pragma unroll
        for (int ti = 0; ti < 4; ++ti)
            acc[ti][tj] = __builtin_amdgcn_mfma_scale_f32_16x16x128_f8f6f4(
                af[ti], bv, acc[ti][tj],
                0, 0,                       // fmtA = fmtB = fp8 e4m3
                0, 0x7F7F7F7F,              // scale_a = 1.0
                0, 0x7F7F7F7F);             // scale_b = 1.0
    }

    // ---- lean epilogue: pos needs only dot; neg via conservative guard ----
    // C/D layout: col = lane&15, row = quad*4 + reg
    float sqjmin = fminf(fminf(sqj[0], sqj[1]), fminf(sqj[2], sqj[3]));
    float posD = 0.f, dotmax = -3e38f, sqimin = 3e38f;

    if (bi != bj) {
        #pragma unroll
        for (int ti = 0; ti < 4; ++ti) {
            #pragma unroll
            for (int r = 0; r < 4; ++r) {
                int gi = giB + ti * 16 + r;
                float sqi = sq[gi]; int yi = y[gi];
                sqimin = fminf(sqimin, sqi);
                #pragma unroll
                for (int tj = 0; tj < 4; ++tj) {
                    float d = acc[ti][tj][r];
                    posD += (yi == yj[tj]) ? d : 0.f;
                    dotmax = fmaxf(dotmax, d);
                }
            }
        }
    } else {
        #pragma unroll
        for (int ti = 0; ti < 4; ++ti) {
            #pragma unroll
            for (int r = 0; r < 4; ++r) {
                int gi = giB + ti * 16 + r;
                float sqi = sq[gi]; int yi = y[gi];
                sqimin = fminf(sqimin, sqi);
                #pragma unroll
                for (int tj = 0; tj < 4; ++tj) {
                    bool self = (gi == gjB + tj * 16);
                    float d = acc[ti][tj][r];
                    posD += (yi == yj[tj] && !self) ? d : 0.f;
                    dotmax = fmaxf(dotmax, self ? -3e38f : d);
                }
            }
        }
    }

    // cold exact-neg fallback (never hot for this data: min nrm ~80 >> 1)
    float negS = 0.f;
    if (2.f * dotmax - sqimin - sqjmin >= -1.f) {
        #pragma unroll
        for (int ti = 0; ti < 4; ++ti)
            #pragma unroll
            for (int r = 0; r < 4; ++r) {
                int gi = giB + ti * 16 + r;
                float sqi = sq[gi]; int yi = y[gi];
                #pragma unroll
                for (int tj = 0; tj < 4; ++tj) {
                    int gj = gjB + tj * 16;
                    if (gi != gj && yi != yj[tj]) {
                        float nrm = fmaf(-2.f, acc[ti][tj][r], sqi + sqj[tj]);
                        negS += fmaxf(1.f - nrm, 0.f);
                    }
                }
            }
    }
    float wgt = (bi == bj) ? 1.f : 2.f;
    float posP = wgt * posD;    // sum of DOTS only (norm part added in finish)
    float negP = wgt * negS;

    #pragma unroll
    for (int off = 32; off > 0; off >>= 1) {
        posP += __shfl_down(posP, off);
        negP += __shfl_down(negP, off);
    }
    float2* wred = (float2*)(smem + SM_RED);   // dedicated region: no extra barrier
    if (lane == 0) wred[wv] = make_float2(posP, negP);
    __syncthreads();
    if (threadIdx.x == 0) {
        float2 a0 = wred[0], a1 = wred[1], a2 = wred[2], a3 = wred[3];
        partials[t] = make_float2(a0.x + a1.x + a2.x + a3.x,
                                  a0.y + a1.y + a2.y + a3.y);
    }
}

// ---- kernel C: histogram + sq-weighted pos-norm + reduce + final ----
__global__ void __launch_bounds__(1024) finish_kernel(
        const float2* __restrict__ partials,
        const int* __restrict__ y,
        const float* __restrict__ sq,
        float* __restrict__ out) {
    __shared__ int hists[16][48];
    __shared__ int htot[48];
    __shared__ float2 red[16];
    __shared__ float swred[16];
    int tid = threadIdx.x, wv = tid >> 6, lane = tid & 63;

    for (int i = tid; i < 16 * 48; i += 1024) ((int*)hists)[i] = 0;
    __syncthreads();

    const int4* y4 = (const int4*)y;
    int4 ya = y4[tid], yb = y4[tid + 1024];
    atomicAdd(&hists[wv][ya.x], 1); atomicAdd(&hists[wv][ya.y], 1);
    atomicAdd(&hists[wv][ya.z], 1); atomicAdd(&hists[wv][ya.w], 1);
    atomicAdd(&hists[wv][yb.x], 1); atomicAdd(&hists[wv][yb.y], 1);
    atomicAdd(&hists[wv][yb.z], 1); atomicAdd(&hists[wv][yb.w], 1);
    __syncthreads();
    if (tid < 48) {
        int nc = 0;
        #pragma unroll
        for (int w = 0; w < 16; ++w) nc += hists[w][tid];
        htot[tid] = nc;
    }
    __syncthreads();

    // S_w = sum_i sq[i]*(n_{y_i}-1);  pos_norm_sum = 2*S_w - 2*pos_dot_sum
    const float4* sq4 = (const float4*)sq;
    float4 sa = sq4[tid], sb = sq4[tid + 1024];
    float sw = sa.x * (float)(htot[ya.x] - 1) + sa.y * (float)(htot[ya.y] - 1)
             + sa.z * (float)(htot[ya.z] - 1) + sa.w * (float)(htot[ya.w] - 1)
             + sb.x * (float)(htot[yb.x] - 1) + sb.y * (float)(htot[yb.y] - 1)
             + sb.z * (float)(htot[yb.z] - 1) + sb.w * (float)(htot[yb.w] - 1);

    float p = 0.f, n = 0.f;
    for (int i = tid; i < NPAIRS; i += 1024) {
        float2 v = partials[i];
        p += v.x; n += v.y;
    }
    #pragma unroll
    for (int off = 32; off > 0; off >>= 1) {
        sw += __shfl_down(sw, off);
        p  += __shfl_down(p, off);
        n  += __shfl_down(n, off);
    }
    if (lane == 0) { red[wv] = make_float2(p, n); swred[wv] = sw; }
    __syncthreads();
    if (tid == 0) {
        float PS = 0.f, NS = 0.f, SW = 0.f;
        #pragma unroll
        for (int w = 0; w < 16; ++w) { PS += red[w].x; NS += red[w].y; SW += swred[w]; }
        long long s2 = 0;
        for (int c = 0; c < NCLS; ++c) { long long h = htot[c]; s2 += h * h; }
        float posc = (float)(s2 - (long long)N_ROWS);
        float negc = (float)((long long)N_ROWS * N_ROWS - s2);
        out[0] = 0.5f * ((2.f * SW - 2.f * PS) / posc + NS / negc);
    }
}

extern "C" void kernel_launch(void* const* d_in, const int* in_sizes, int n_in,
                              void* d_out, int out_size, void* d_ws, size_t ws_size,
                              hipStream_t stream) {
    const float* x = (const float*)d_in[0];
    const int*   y = (const int*)d_in[1];
    float* out = (float*)d_out;

    char* ws = (char*)d_ws;
    float2*         partials = (float2*)ws;                    // 2080 float2 (16640 B)
    float*          sq       = (float*)(ws + 16896);           // 8192 floats
    unsigned char*  xq       = (unsigned char*)(ws + 49920);   // 8192*128 fp8 (1 MB)

    prep_kernel<<<N_ROWS / 8, 256, 0, stream>>>(x, sq, xq);
    tile_kernel<<<NPAIRS, 256, 0, stream>>>(xq, sq, y, partials);
    finish_kernel<<<1, 1024, 0, stream>>>(partials, y, sq, out);
}